// Round 9
// baseline (300.688 us; speedup 1.0000x reference)
//
#include <hip/hip_runtime.h>
#include <stdint.h>

typedef __attribute__((ext_vector_type(8))) short bf16x8;   // 8 bf16 = 4 VGPR (MFMA A/B frag)
typedef __attribute__((ext_vector_type(4))) float f32x4;    // MFMA C/D frag
typedef __attribute__((ext_vector_type(4))) unsigned short us4;
typedef __attribute__((ext_vector_type(8))) unsigned short us8;

__device__ __forceinline__ unsigned short f2bf(float f) {   // RNE f32 -> bf16
  union { float f; unsigned u; } x; x.f = f;
  unsigned r = x.u + 0x7FFFu + ((x.u >> 16) & 1u);
  return (unsigned short)(r >> 16);
}
__device__ __forceinline__ float bf2f(unsigned short h) {
  union { unsigned u; float f; } x; x.u = ((unsigned)h) << 16;
  return x.f;
}

// async global->LDS, 16B per lane; LDS dest is wave-uniform base + lane*16
#define GL2LDS(g, l) __builtin_amdgcn_global_load_lds( \
    (const __attribute__((address_space(1))) unsigned int*)(g), \
    (__attribute__((address_space(3))) unsigned int*)(l), 16, 0, 0)

// ---------------- fused prep: x cvt + weight cvt + out_proj transpose ----------------
__global__ __launch_bounds__(256)
void prep(const float* __restrict__ x,
          const float* __restrict__ wq, const float* __restrict__ wk,
          const float* __restrict__ wv, const float* __restrict__ wo,
          unsigned short* __restrict__ xb,
          unsigned short* __restrict__ wqb, unsigned short* __restrict__ wkb,
          unsigned short* __restrict__ wvb, unsigned short* __restrict__ opT)
{
  __shared__ float t[32][33];
  const int b = blockIdx.x;
  if (b < 11264) {
    const float* in; unsigned short* out; int i;
    if (b < 8192) { in = x; out = xb; i = b * 256 + threadIdx.x; }
    else {
      const int w = (b - 8192) >> 10;
      in  = (w == 0) ? wq : (w == 1) ? wk : wv;
      out = (w == 0) ? wqb : (w == 1) ? wkb : wvb;
      i = ((b - 8192) & 1023) * 256 + threadIdx.x;
    }
    const float4 f = ((const float4*)in)[i];
    us4 v;
    v[0] = f2bf(f.x); v[1] = f2bf(f.y); v[2] = f2bf(f.z); v[3] = f2bf(f.w);
    ((us4*)out)[i] = v;
  } else {
    const int tb = b - 11264;
    const int bx = (tb & 31) * 32, by = (tb >> 5) * 32;
    const int tx = threadIdx.x & 31, ty = threadIdx.x >> 5;
#pragma unroll
    for (int i = 0; i < 32; i += 8)
      t[ty + i][tx] = wo[(size_t)(by + ty + i) * 1024 + bx + tx];
    __syncthreads();
#pragma unroll
    for (int i = 0; i < 32; i += 8)
      opT[(size_t)(bx + ty + i) * 1024 + by + tx] = f2bf(t[tx][ty + i]);
  }
}

// ---------------- fused QKV projection ----------------
// blockIdx.x in [0,24): weight = x>>3, n0 = (x&7)*128.
// Q,K row-major via LDS-staged full-line stores; V stored transposed VT[b][d][s].
__global__ __launch_bounds__(256, 4)
void gemm_qkv(const unsigned short* __restrict__ xb,
              const unsigned short* __restrict__ wq, const unsigned short* __restrict__ wk,
              const unsigned short* __restrict__ wv,
              unsigned short* __restrict__ Q, unsigned short* __restrict__ Kb,
              unsigned short* __restrict__ VT)
{
  const int m0 = blockIdx.y * 128;
  const int wsel = blockIdx.x >> 3;
  const int n0 = (blockIdx.x & 7) * 128;
  const unsigned short* W = (wsel == 0) ? wq : (wsel == 1) ? wk : wv;

  const int tid = threadIdx.x;
  const int lane = tid & 63, wave = tid >> 6;
  const int quad = lane >> 4, l16 = lane & 15;
  const int wm = wave & 1, wn = wave >> 1;

  __shared__ __align__(16) char smem[16384];
  char* ldsA = smem; char* ldsW = smem + 8192;
  const int wrow = tid >> 2;
  const unsigned short* Ab = xb + (size_t)m0 * 1024 + (tid & 3) * 8;
  const unsigned short* Wb = W  + (size_t)n0 * 1024 + (tid & 3) * 8;

  f32x4 acc[4][4] = {};
  for (int k0 = 0; k0 < 1024; k0 += 32) {
    __syncthreads();
    GL2LDS(Ab + (size_t)wrow * 1024 + k0,        ldsA +        tid * 16);
    GL2LDS(Ab + (size_t)(wrow + 64) * 1024 + k0, ldsA + 4096 + tid * 16);
    GL2LDS(Wb + (size_t)wrow * 1024 + k0,        ldsW +        tid * 16);
    GL2LDS(Wb + (size_t)(wrow + 64) * 1024 + k0, ldsW + 4096 + tid * 16);
    __syncthreads();
    bf16x8 af[4], wf[4];
#pragma unroll
    for (int mt = 0; mt < 4; ++mt)
      af[mt] = *(const bf16x8*)(ldsA + ((wm * 64 + mt * 16 + l16) * 32 + quad * 8) * 2);
#pragma unroll
    for (int nt = 0; nt < 4; ++nt)
      wf[nt] = *(const bf16x8*)(ldsW + ((wn * 64 + nt * 16 + l16) * 32 + quad * 8) * 2);
#pragma unroll
    for (int mt = 0; mt < 4; ++mt)
#pragma unroll
      for (int nt = 0; nt < 4; ++nt)
        acc[mt][nt] = __builtin_amdgcn_mfma_f32_16x16x32_bf16(af[mt], wf[nt], acc[mt][nt], 0, 0, 0);
  }

  __syncthreads();   // staging reads done; LDS free for epilogue patches
  const int gr0 = m0 + wm * 64;
  const int gc0 = n0 + wn * 64;
  if (wsel == 2) {
    // VT[b][d][s]: us4 along s (4 consecutive rows)
#pragma unroll
    for (int mt = 0; mt < 4; ++mt)
#pragma unroll
      for (int nt = 0; nt < 4; ++nt) {
        const int gr = gr0 + mt * 16 + quad * 4;
        const int gc = gc0 + nt * 16 + l16;
        us4 v;
#pragma unroll
        for (int r = 0; r < 4; ++r) v[r] = f2bf(acc[mt][nt][r]);
        const int b = gr >> 11, s = gr & 2047;
        *(us4*)(VT + (size_t)b * (1024 * 2048) + (size_t)gc * 2048 + s) = v;
      }
  } else {
    unsigned short* C = (wsel == 0) ? Q : Kb;
    unsigned short* patch = (unsigned short*)smem + wave * (16 * 72);
#pragma unroll
    for (int mt = 0; mt < 4; ++mt) {
#pragma unroll
      for (int nt = 0; nt < 4; ++nt)
#pragma unroll
        for (int r = 0; r < 4; ++r)
          patch[(quad * 4 + r) * 72 + nt * 16 + l16] = f2bf(acc[mt][nt][r]);
      __builtin_amdgcn_wave_barrier();
#pragma unroll
      for (int j = 0; j < 2; ++j) {
        const int rr = j * 8 + (lane >> 3);
        us8 v = *(const us8*)&patch[rr * 72 + (lane & 7) * 8];
        *(us8*)&C[(size_t)(gr0 + mt * 16 + rr) * 1024 + gc0 + (lane & 7) * 8] = v;
      }
      __builtin_amdgcn_wave_barrier();
    }
  }
}

// ---------------- generic bf16 GEMM: C = A @ W^T ----------------
// MODE 0: C bf16 (LDS-staged us8 stores); MODE 1: C f32 (LDS-staged float4 stores).
// CAUSAL: block skip. PVLIM: Keff = m0+128.
template<int MODE, bool CAUSAL, bool PVLIM>
__global__ __launch_bounds__(256, 4)
void gemm_bt(const unsigned short* __restrict__ A, const unsigned short* __restrict__ W,
             void* __restrict__ Cv, int lda, int ldw, int ldc, int K,
             long long sAz, long long sWz, long long sCz)
{
  const int m0 = blockIdx.y * 128;
  const int n0 = blockIdx.x * 128;
  if (CAUSAL && n0 > m0 + 127) return;
  const int z = blockIdx.z;
  A += (size_t)z * sAz;
  W += (size_t)z * sWz;

  const int tid = threadIdx.x;
  const int lane = tid & 63, wave = tid >> 6;
  const int quad = lane >> 4, l16 = lane & 15;
  const int wm = wave & 1, wn = wave >> 1;

  __shared__ __align__(16) char smem[(MODE == 1) ? 17408 : 16384];
  char* ldsA = smem; char* ldsW = smem + 8192;
  const int wrow = tid >> 2;
  const unsigned short* Ab = A + (size_t)m0 * lda + (tid & 3) * 8;
  const unsigned short* Wb = W + (size_t)n0 * ldw + (tid & 3) * 8;

  f32x4 acc[4][4] = {};
  const int Keff = PVLIM ? ((m0 + 128 < K) ? (m0 + 128) : K) : K;

  for (int k0 = 0; k0 < Keff; k0 += 32) {
    __syncthreads();
    GL2LDS(Ab + (size_t)wrow * lda + k0,        ldsA +        tid * 16);
    GL2LDS(Ab + (size_t)(wrow + 64) * lda + k0, ldsA + 4096 + tid * 16);
    GL2LDS(Wb + (size_t)wrow * ldw + k0,        ldsW +        tid * 16);
    GL2LDS(Wb + (size_t)(wrow + 64) * ldw + k0, ldsW + 4096 + tid * 16);
    __syncthreads();
    bf16x8 af[4], wf[4];
#pragma unroll
    for (int mt = 0; mt < 4; ++mt)
      af[mt] = *(const bf16x8*)(ldsA + ((wm * 64 + mt * 16 + l16) * 32 + quad * 8) * 2);
#pragma unroll
    for (int nt = 0; nt < 4; ++nt)
      wf[nt] = *(const bf16x8*)(ldsW + ((wn * 64 + nt * 16 + l16) * 32 + quad * 8) * 2);
#pragma unroll
    for (int mt = 0; mt < 4; ++mt)
#pragma unroll
      for (int nt = 0; nt < 4; ++nt)
        acc[mt][nt] = __builtin_amdgcn_mfma_f32_16x16x32_bf16(af[mt], wf[nt], acc[mt][nt], 0, 0, 0);
  }

  __syncthreads();   // staging reads done; LDS free for epilogue patches
  const int gr0 = m0 + wm * 64;
  const int gc0 = n0 + wn * 64;
  if (MODE == 0) {
    unsigned short* C = (unsigned short*)Cv + (size_t)z * sCz;
    unsigned short* patch = (unsigned short*)smem + wave * (16 * 72);
#pragma unroll
    for (int mt = 0; mt < 4; ++mt) {
#pragma unroll
      for (int nt = 0; nt < 4; ++nt)
#pragma unroll
        for (int r = 0; r < 4; ++r)
          patch[(quad * 4 + r) * 72 + nt * 16 + l16] = f2bf(acc[mt][nt][r]);
      __builtin_amdgcn_wave_barrier();
#pragma unroll
      for (int j = 0; j < 2; ++j) {
        const int rr = j * 8 + (lane >> 3);
        us8 v = *(const us8*)&patch[rr * 72 + (lane & 7) * 8];
        *(us8*)&C[(size_t)(gr0 + mt * 16 + rr) * ldc + gc0 + (lane & 7) * 8] = v;
      }
      __builtin_amdgcn_wave_barrier();
    }
  } else {
    float* C = (float*)Cv + (size_t)z * sCz;
    float* patch = (float*)smem + wave * (16 * 68);
#pragma unroll
    for (int mt = 0; mt < 4; ++mt) {
#pragma unroll
      for (int nt = 0; nt < 4; ++nt)
#pragma unroll
        for (int r = 0; r < 4; ++r)
          patch[(quad * 4 + r) * 68 + nt * 16 + l16] = acc[mt][nt][r];
      __builtin_amdgcn_wave_barrier();
#pragma unroll
      for (int j = 0; j < 4; ++j) {
        const int rr = j * 4 + (lane >> 4);
        float4 v = *(const float4*)&patch[rr * 68 + (lane & 15) * 4];
        *(float4*)&C[(size_t)(gr0 + mt * 16 + rr) * ldc + gc0 + (lane & 15) * 4] = v;
      }
      __builtin_amdgcn_wave_barrier();
    }
  }
}

// causal softmax; blockIdx.x = b*2048 + r; valid cols [0,r]; scale 1/32 pre-exp.
// Touches only cols [0, ((r>>7)+1)*128) — exactly the band the PVLIM GEMM consumes.
__global__ __launch_bounds__(256)
void softmax_causal(unsigned short* __restrict__ SP)
{
  const int gid = blockIdx.x;
  const int r   = gid & 2047;
  const int tid = threadIdx.x;
  unsigned short* row = SP + (size_t)gid * 2048;
  const int n  = r + 1;
  const int nb = ((r >> 7) + 1) << 7;
  const int it = nb >> 8;
  const int rem = nb & 255;

  float vals[8];
  float lmax = -1e30f;
#pragma unroll
  for (int i = 0; i < 8; ++i) {
    const int c = tid + i * 256;
    if (i < it || (i == it && tid < rem)) {
      const float f = bf2f(row[c]);
      vals[i] = f;
      if (c < n) lmax = fmaxf(lmax, f);
    }
  }
#pragma unroll
  for (int m = 32; m; m >>= 1) lmax = fmaxf(lmax, __shfl_xor(lmax, m, 64));
  __shared__ float redm[4], reds[4];
  if ((tid & 63) == 0) redm[tid >> 6] = lmax;
  __syncthreads();
  lmax = fmaxf(fmaxf(redm[0], redm[1]), fmaxf(redm[2], redm[3]));

  float e[8];
  float lsum = 0.f;
#pragma unroll
  for (int i = 0; i < 8; ++i) {
    const int c = tid + i * 256;
    const float ev = (c < n) ? __expf((vals[i] - lmax) * 0.03125f) : 0.f;
    e[i] = ev;
    lsum += ev;
  }
#pragma unroll
  for (int m = 32; m; m >>= 1) lsum += __shfl_xor(lsum, m, 64);
  if ((tid & 63) == 0) reds[tid >> 6] = lsum;
  __syncthreads();
  lsum = reds[0] + reds[1] + reds[2] + reds[3];
  const float inv = 1.f / lsum;
#pragma unroll
  for (int i = 0; i < 8; ++i) {
    const int c = tid + i * 256;
    if (i < it || (i == it && tid < rem))
      row[c] = f2bf(e[i] * inv);
  }
}

extern "C" void kernel_launch(void* const* d_in, const int* in_sizes, int n_in,
                              void* d_out, int out_size, void* d_ws, size_t ws_size,
                              hipStream_t stream)
{
  (void)in_sizes; (void)n_in; (void)out_size; (void)ws_size;
  // dict order: k, q, v, out_proj, x — f32 inputs, f32 output
  const float* wk_f = (const float*)d_in[0];
  const float* wq_f = (const float*)d_in[1];
  const float* wv_f = (const float*)d_in[2];
  const float* wo_f = (const float*)d_in[3];
  const float* x_f  = (const float*)d_in[4];
  float* out = (float*)d_out;

  // ws layout (98 MiB):
  char* p = (char*)d_ws;
  unsigned short* xb  = (unsigned short*)(p);                       // [0,16M)
  unsigned short* QO  = (unsigned short*)(p + ((size_t)16 << 20));  // [16,32M): Q, then O
  unsigned short* Kb  = (unsigned short*)(p + ((size_t)32 << 20));  // [32,48M)
  unsigned short* VT  = (unsigned short*)(p + ((size_t)48 << 20));  // [48,64M): [B][d][S]
  unsigned short* SP  = (unsigned short*)(p + ((size_t)64 << 20));  // [64,96M): [B][S][S]
  unsigned short* wqb = (unsigned short*)(p + ((size_t)64 << 20));  // alias (dead before scores)
  unsigned short* wkb = (unsigned short*)(p + ((size_t)66 << 20));
  unsigned short* wvb = (unsigned short*)(p + ((size_t)68 << 20));
  unsigned short* opT = (unsigned short*)(p + ((size_t)96 << 20));  // [96,98M)

  dim3 blk(256);

  prep<<<dim3(12288), blk, 0, stream>>>(x_f, wq_f, wk_f, wv_f, wo_f, xb, wqb, wkb, wvb, opT);

  // fused QKV: M=8192, N=3*1024, K=1024
  gemm_qkv<<<dim3(24, 64), blk, 0, stream>>>(xb, wqb, wkb, wvb, QO, Kb, VT);

  // scores (all batches): [B][2048,2048] = Q @ K^T, causal skip
  gemm_bt<0, true, false><<<dim3(16, 16, 4), blk, 0, stream>>>(QO, Kb, SP, 1024, 1024, 2048, 1024,
      (long long)2048 * 1024, (long long)2048 * 1024, (long long)2048 * 2048);

  // P = causal_softmax(scores/32), in place, all batches
  softmax_causal<<<dim3(8192), blk, 0, stream>>>(SP);

  // O = P @ V (all batches), K limited to diagonal; O overwrites Q
  gemm_bt<0, false, true><<<dim3(8, 16, 4), blk, 0, stream>>>(SP, VT, QO, 2048, 2048, 1024, 2048,
      (long long)2048 * 2048, (long long)1024 * 2048, (long long)2048 * 1024);

  // out = O @ out_proj^T -> f32 d_out
  gemm_bt<1, false, false><<<dim3(8, 64, 1), blk, 0, stream>>>(QO, opT, out, 1024, 1024, 1024, 1024,
      0, 0, 0);
}

// Round 10
// 289.049 us; speedup vs baseline: 1.0403x; 1.0403x over previous
//
#include <hip/hip_runtime.h>
#include <stdint.h>

typedef __attribute__((ext_vector_type(8))) short bf16x8;   // 8 bf16 = 4 VGPR (MFMA A/B frag)
typedef __attribute__((ext_vector_type(4))) float f32x4;    // MFMA C/D frag
typedef __attribute__((ext_vector_type(4))) unsigned short us4;
typedef __attribute__((ext_vector_type(8))) unsigned short us8;

__device__ __forceinline__ unsigned short f2bf(float f) {   // RNE f32 -> bf16
  union { float f; unsigned u; } x; x.f = f;
  unsigned r = x.u + 0x7FFFu + ((x.u >> 16) & 1u);
  return (unsigned short)(r >> 16);
}
__device__ __forceinline__ float bf2f(unsigned short h) {
  union { unsigned u; float f; } x; x.u = ((unsigned)h) << 16;
  return x.f;
}

// async global->LDS, 16B per lane; LDS dest is wave-uniform base + lane*16
#define GL2LDS(g, l) __builtin_amdgcn_global_load_lds( \
    (const __attribute__((address_space(1))) unsigned int*)(g), \
    (__attribute__((address_space(3))) unsigned int*)(l), 16, 0, 0)

// ---------------- fused prep ----------------
// [0,8192): x f32->bf16
// [8192,9216): wq cvt      [9216,10240): wk cvt
// [10240,11264): v transpose->vtb      [11264,12288): out_proj transpose->opT
__global__ __launch_bounds__(256)
void prep(const float* __restrict__ x,
          const float* __restrict__ wq, const float* __restrict__ wk,
          const float* __restrict__ wv, const float* __restrict__ wo,
          unsigned short* __restrict__ xb,
          unsigned short* __restrict__ wqb, unsigned short* __restrict__ wkb,
          unsigned short* __restrict__ vtb, unsigned short* __restrict__ opT)
{
  __shared__ float t[32][33];
  const int b = blockIdx.x;
  if (b < 10240) {
    const float* in; unsigned short* out; int i;
    if (b < 8192)      { in = x;  out = xb;  i = b * 256 + threadIdx.x; }
    else if (b < 9216) { in = wq; out = wqb; i = (b - 8192) * 256 + threadIdx.x; }
    else               { in = wk; out = wkb; i = (b - 9216) * 256 + threadIdx.x; }
    const float4 f = ((const float4*)in)[i];
    us4 v;
    v[0] = f2bf(f.x); v[1] = f2bf(f.y); v[2] = f2bf(f.z); v[3] = f2bf(f.w);
    ((us4*)out)[i] = v;
  } else {
    const float* in = (b < 11264) ? wv : wo;
    unsigned short* out = (b < 11264) ? vtb : opT;
    const int tb = (b < 11264) ? (b - 10240) : (b - 11264);
    const int bx = (tb & 31) * 32, by = (tb >> 5) * 32;
    const int tx = threadIdx.x & 31, ty = threadIdx.x >> 5;
#pragma unroll
    for (int i = 0; i < 32; i += 8)
      t[ty + i][tx] = in[(size_t)(by + ty + i) * 1024 + bx + tx];
    __syncthreads();
#pragma unroll
    for (int i = 0; i < 32; i += 8)
      out[(size_t)(bx + ty + i) * 1024 + by + tx] = f2bf(t[tx][ty + i]);
  }
}

// ---------------- fused QKV' projection ----------------
// blockIdx.x in [0,24): weight = x>>3, n0 = (x&7)*128.
// wsel 0: Q = x@wq^T (row-major), 1: K = x@wk^T (row-major),
// wsel 2: V' = x@Wct^T stored transposed VT[b][j][s] (V' = x @ (v^T@out_proj)).
__global__ __launch_bounds__(256, 4)
void gemm_qkv(const unsigned short* __restrict__ xb,
              const unsigned short* __restrict__ wq, const unsigned short* __restrict__ wk,
              const unsigned short* __restrict__ wct,
              unsigned short* __restrict__ Q, unsigned short* __restrict__ Kb,
              unsigned short* __restrict__ VT)
{
  const int m0 = blockIdx.y * 128;
  const int wsel = blockIdx.x >> 3;
  const int n0 = (blockIdx.x & 7) * 128;
  const unsigned short* W = (wsel == 0) ? wq : (wsel == 1) ? wk : wct;

  const int tid = threadIdx.x;
  const int lane = tid & 63, wave = tid >> 6;
  const int quad = lane >> 4, l16 = lane & 15;
  const int wm = wave & 1, wn = wave >> 1;

  __shared__ __align__(16) char smem[16384];
  char* ldsA = smem; char* ldsW = smem + 8192;
  const int wrow = tid >> 2;
  const unsigned short* Ab = xb + (size_t)m0 * 1024 + (tid & 3) * 8;
  const unsigned short* Wb = W  + (size_t)n0 * 1024 + (tid & 3) * 8;

  f32x4 acc[4][4] = {};
  for (int k0 = 0; k0 < 1024; k0 += 32) {
    __syncthreads();
    GL2LDS(Ab + (size_t)wrow * 1024 + k0,        ldsA +        tid * 16);
    GL2LDS(Ab + (size_t)(wrow + 64) * 1024 + k0, ldsA + 4096 + tid * 16);
    GL2LDS(Wb + (size_t)wrow * 1024 + k0,        ldsW +        tid * 16);
    GL2LDS(Wb + (size_t)(wrow + 64) * 1024 + k0, ldsW + 4096 + tid * 16);
    __syncthreads();
    bf16x8 af[4], wf[4];
#pragma unroll
    for (int mt = 0; mt < 4; ++mt)
      af[mt] = *(const bf16x8*)(ldsA + ((wm * 64 + mt * 16 + l16) * 32 + quad * 8) * 2);
#pragma unroll
    for (int nt = 0; nt < 4; ++nt)
      wf[nt] = *(const bf16x8*)(ldsW + ((wn * 64 + nt * 16 + l16) * 32 + quad * 8) * 2);
#pragma unroll
    for (int mt = 0; mt < 4; ++mt)
#pragma unroll
      for (int nt = 0; nt < 4; ++nt)
        acc[mt][nt] = __builtin_amdgcn_mfma_f32_16x16x32_bf16(af[mt], wf[nt], acc[mt][nt], 0, 0, 0);
  }

  __syncthreads();
  const int gr0 = m0 + wm * 64;
  const int gc0 = n0 + wn * 64;
  if (wsel == 2) {
#pragma unroll
    for (int mt = 0; mt < 4; ++mt)
#pragma unroll
      for (int nt = 0; nt < 4; ++nt) {
        const int gr = gr0 + mt * 16 + quad * 4;
        const int gc = gc0 + nt * 16 + l16;
        us4 v;
#pragma unroll
        for (int r = 0; r < 4; ++r) v[r] = f2bf(acc[mt][nt][r]);
        const int b = gr >> 11, s = gr & 2047;
        *(us4*)(VT + (size_t)b * (1024 * 2048) + (size_t)gc * 2048 + s) = v;
      }
  } else {
    unsigned short* C = (wsel == 0) ? Q : Kb;
    unsigned short* patch = (unsigned short*)smem + wave * (16 * 72);
#pragma unroll
    for (int mt = 0; mt < 4; ++mt) {
#pragma unroll
      for (int nt = 0; nt < 4; ++nt)
#pragma unroll
        for (int r = 0; r < 4; ++r)
          patch[(quad * 4 + r) * 72 + nt * 16 + l16] = f2bf(acc[mt][nt][r]);
      __builtin_amdgcn_wave_barrier();
#pragma unroll
      for (int j = 0; j < 2; ++j) {
        const int rr = j * 8 + (lane >> 3);
        us8 v = *(const us8*)&patch[rr * 72 + (lane & 7) * 8];
        *(us8*)&C[(size_t)(gr0 + mt * 16 + rr) * 1024 + gc0 + (lane & 7) * 8] = v;
      }
      __builtin_amdgcn_wave_barrier();
    }
  }
}

// ---------------- generic bf16 GEMM: C = A @ W^T ----------------
// MODE 0: C bf16 (LDS-staged us8 stores); MODE 1: C f32 (LDS-staged float4 stores).
// CAUSAL: block skip. PVLIM: Keff = m0+128.
template<int MODE, bool CAUSAL, bool PVLIM>
__global__ __launch_bounds__(256, 4)
void gemm_bt(const unsigned short* __restrict__ A, const unsigned short* __restrict__ W,
             void* __restrict__ Cv, int lda, int ldw, int ldc, int K,
             long long sAz, long long sWz, long long sCz)
{
  const int m0 = blockIdx.y * 128;
  const int n0 = blockIdx.x * 128;
  if (CAUSAL && n0 > m0 + 127) return;
  const int z = blockIdx.z;
  A += (size_t)z * sAz;
  W += (size_t)z * sWz;

  const int tid = threadIdx.x;
  const int lane = tid & 63, wave = tid >> 6;
  const int quad = lane >> 4, l16 = lane & 15;
  const int wm = wave & 1, wn = wave >> 1;

  __shared__ __align__(16) char smem[(MODE == 1) ? 17408 : 16384];
  char* ldsA = smem; char* ldsW = smem + 8192;
  const int wrow = tid >> 2;
  const unsigned short* Ab = A + (size_t)m0 * lda + (tid & 3) * 8;
  const unsigned short* Wb = W + (size_t)n0 * ldw + (tid & 3) * 8;

  f32x4 acc[4][4] = {};
  const int Keff = PVLIM ? ((m0 + 128 < K) ? (m0 + 128) : K) : K;

  for (int k0 = 0; k0 < Keff; k0 += 32) {
    __syncthreads();
    GL2LDS(Ab + (size_t)wrow * lda + k0,        ldsA +        tid * 16);
    GL2LDS(Ab + (size_t)(wrow + 64) * lda + k0, ldsA + 4096 + tid * 16);
    GL2LDS(Wb + (size_t)wrow * ldw + k0,        ldsW +        tid * 16);
    GL2LDS(Wb + (size_t)(wrow + 64) * ldw + k0, ldsW + 4096 + tid * 16);
    __syncthreads();
    bf16x8 af[4], wf[4];
#pragma unroll
    for (int mt = 0; mt < 4; ++mt)
      af[mt] = *(const bf16x8*)(ldsA + ((wm * 64 + mt * 16 + l16) * 32 + quad * 8) * 2);
#pragma unroll
    for (int nt = 0; nt < 4; ++nt)
      wf[nt] = *(const bf16x8*)(ldsW + ((wn * 64 + nt * 16 + l16) * 32 + quad * 8) * 2);
#pragma unroll
    for (int mt = 0; mt < 4; ++mt)
#pragma unroll
      for (int nt = 0; nt < 4; ++nt)
        acc[mt][nt] = __builtin_amdgcn_mfma_f32_16x16x32_bf16(af[mt], wf[nt], acc[mt][nt], 0, 0, 0);
  }

  __syncthreads();
  const int gr0 = m0 + wm * 64;
  const int gc0 = n0 + wn * 64;
  if (MODE == 0) {
    unsigned short* C = (unsigned short*)Cv + (size_t)z * sCz;
    unsigned short* patch = (unsigned short*)smem + wave * (16 * 72);
#pragma unroll
    for (int mt = 0; mt < 4; ++mt) {
#pragma unroll
      for (int nt = 0; nt < 4; ++nt)
#pragma unroll
        for (int r = 0; r < 4; ++r)
          patch[(quad * 4 + r) * 72 + nt * 16 + l16] = f2bf(acc[mt][nt][r]);
      __builtin_amdgcn_wave_barrier();
#pragma unroll
      for (int j = 0; j < 2; ++j) {
        const int rr = j * 8 + (lane >> 3);
        us8 v = *(const us8*)&patch[rr * 72 + (lane & 7) * 8];
        *(us8*)&C[(size_t)(gr0 + mt * 16 + rr) * ldc + gc0 + (lane & 7) * 8] = v;
      }
      __builtin_amdgcn_wave_barrier();
    }
  } else {
    float* C = (float*)Cv + (size_t)z * sCz;
    float* patch = (float*)smem + wave * (16 * 68);
#pragma unroll
    for (int mt = 0; mt < 4; ++mt) {
#pragma unroll
      for (int nt = 0; nt < 4; ++nt)
#pragma unroll
        for (int r = 0; r < 4; ++r)
          patch[(quad * 4 + r) * 68 + nt * 16 + l16] = acc[mt][nt][r];
      __builtin_amdgcn_wave_barrier();
#pragma unroll
      for (int j = 0; j < 4; ++j) {
        const int rr = j * 4 + (lane >> 4);
        float4 v = *(const float4*)&patch[rr * 68 + (lane & 15) * 4];
        *(float4*)&C[(size_t)(gr0 + mt * 16 + rr) * ldc + gc0 + (lane & 15) * 4] = v;
      }
      __builtin_amdgcn_wave_barrier();
    }
  }
}

// causal softmax; blockIdx.x = b*2048 + r; valid cols [0,r]; scale 1/32 pre-exp.
// Touches only cols [0, ((r>>7)+1)*128) — exactly the band the PVLIM GEMM consumes.
__global__ __launch_bounds__(256)
void softmax_causal(unsigned short* __restrict__ SP)
{
  const int gid = blockIdx.x;
  const int r   = gid & 2047;
  const int tid = threadIdx.x;
  unsigned short* row = SP + (size_t)gid * 2048;
  const int n  = r + 1;
  const int nb = ((r >> 7) + 1) << 7;
  const int it = nb >> 8;
  const int rem = nb & 255;

  float vals[8];
  float lmax = -1e30f;
#pragma unroll
  for (int i = 0; i < 8; ++i) {
    const int c = tid + i * 256;
    if (i < it || (i == it && tid < rem)) {
      const float f = bf2f(row[c]);
      vals[i] = f;
      if (c < n) lmax = fmaxf(lmax, f);
    }
  }
#pragma unroll
  for (int m = 32; m; m >>= 1) lmax = fmaxf(lmax, __shfl_xor(lmax, m, 64));
  __shared__ float redm[4], reds[4];
  if ((tid & 63) == 0) redm[tid >> 6] = lmax;
  __syncthreads();
  lmax = fmaxf(fmaxf(redm[0], redm[1]), fmaxf(redm[2], redm[3]));

  float e[8];
  float lsum = 0.f;
#pragma unroll
  for (int i = 0; i < 8; ++i) {
    const int c = tid + i * 256;
    const float ev = (c < n) ? __expf((vals[i] - lmax) * 0.03125f) : 0.f;
    e[i] = ev;
    lsum += ev;
  }
#pragma unroll
  for (int m = 32; m; m >>= 1) lsum += __shfl_xor(lsum, m, 64);
  if ((tid & 63) == 0) reds[tid >> 6] = lsum;
  __syncthreads();
  lsum = reds[0] + reds[1] + reds[2] + reds[3];
  const float inv = 1.f / lsum;
#pragma unroll
  for (int i = 0; i < 8; ++i) {
    const int c = tid + i * 256;
    if (i < it || (i == it && tid < rem))
      row[c] = f2bf(e[i] * inv);
  }
}

extern "C" void kernel_launch(void* const* d_in, const int* in_sizes, int n_in,
                              void* d_out, int out_size, void* d_ws, size_t ws_size,
                              hipStream_t stream)
{
  (void)in_sizes; (void)n_in; (void)out_size; (void)ws_size;
  // dict order: k, q, v, out_proj, x — f32 inputs, f32 output
  const float* wk_f = (const float*)d_in[0];
  const float* wq_f = (const float*)d_in[1];
  const float* wv_f = (const float*)d_in[2];
  const float* wo_f = (const float*)d_in[3];
  const float* x_f  = (const float*)d_in[4];
  float* out = (float*)d_out;

  // ws layout (98 MiB):
  char* p = (char*)d_ws;
  unsigned short* xb   = (unsigned short*)(p);                       // [0,16M)
  unsigned short* Q    = (unsigned short*)(p + ((size_t)16 << 20));  // [16,32M)
  unsigned short* Kb   = (unsigned short*)(p + ((size_t)32 << 20));  // [32,48M)
  unsigned short* VT   = (unsigned short*)(p + ((size_t)48 << 20));  // [48,64M): V'^T [B][j][s]
  unsigned short* SP   = (unsigned short*)(p + ((size_t)64 << 20));  // [64,96M): [B][S][S]
  unsigned short* wqb  = (unsigned short*)(p + ((size_t)64 << 20));  // aliases (dead before scores)
  unsigned short* wkb  = (unsigned short*)(p + ((size_t)66 << 20));
  unsigned short* vtb  = (unsigned short*)(p + ((size_t)68 << 20));  // v^T bf16
  unsigned short* wctb = (unsigned short*)(p + ((size_t)70 << 20));  // Wct = out_proj^T-combined weight
  unsigned short* opT  = (unsigned short*)(p + ((size_t)96 << 20));  // [96,98M)

  dim3 blk(256);

  // conversions + transposes (x, wq, wk, v^T, out_proj^T)
  prep<<<dim3(12288), blk, 0, stream>>>(x_f, wq_f, wk_f, wv_f, wo_f, xb, wqb, wkb, vtb, opT);

  // Wct[j][e] = sum_d out_proj[d][j] * v[d][e]  (= (v^T @ out_proj)^T), tiny GEMM
  gemm_bt<0, false, false><<<dim3(8, 8, 1), blk, 0, stream>>>(opT, vtb, wctb,
      1024, 1024, 1024, 1024, 0, 0, 0);

  // fused Q/K/V' projections: M=8192, N=3*1024, K=1024
  gemm_qkv<<<dim3(24, 64), blk, 0, stream>>>(xb, wqb, wkb, wctb, Q, Kb, VT);

  // scores (all batches): [B][2048,2048] = Q @ K^T, causal skip
  gemm_bt<0, true, false><<<dim3(16, 16, 4), blk, 0, stream>>>(Q, Kb, SP, 1024, 1024, 2048, 1024,
      (long long)2048 * 1024, (long long)2048 * 1024, (long long)2048 * 2048);

  // P = causal_softmax(scores/32), in place, all batches
  softmax_causal<<<dim3(8192), blk, 0, stream>>>(SP);

  // out = P @ V' (all batches), K limited to diagonal, f32 store DIRECTLY to d_out
  gemm_bt<1, false, true><<<dim3(8, 16, 4), blk, 0, stream>>>(SP, VT, out, 2048, 2048, 1024, 2048,
      (long long)2048 * 2048, (long long)1024 * 2048, (long long)2048 * 1024);
}